// Round 1
// 69.358 us; speedup vs baseline: 1.0073x; 1.0073x over previous
//
#include <hip/hip_runtime.h>

// Preisach hysteresis, N=256 mesh, M=4096 steps.
// Row-compressed state: row i is +1 for j<c_i, -1 for c_i<=j<=i (single int c_i).
//   up event (hc>hp):   c_i = i+1 for all i with lin[i] < hc   (iup = #lin<hc)
//   down event (hc<hp): c_i = min(c_i, jdn), jdn = #lin<=hc
// b[t] = (2*sum_i Pref[i][c_i(t)] - Stot) / Stot,  Pref = row-exclusive prefix of softplus.
// Init (reference's wrap-around t=0 sweep-up, hc=1.0): rows 0..254 all +1, row 255 all -1.
//
// R7: replace the data-dependent backward scan entirely with a deterministic
// two-level operator-prefix. Per-row per-step ops form a 2-word semigroup:
//   op = MIN(m):   c -> min(c, m)        encoded  m          (bit16 clear)
//   op = CONST(v): c -> v                encoded  0x10000|v
// compose(a,b) (a first) = b.const ? b : (a.type | min(a.m, b.m))  -- 4 VALU ops.
// k_prep event blocks (which already hold their 256 codes in LDS) emit per-row
// chunk ops (16 steps) and superchunk ops (256 steps). k_main block b rebuilds
// its incoming state with <=15 coalesced superop loads + 4 coalesced int4
// chunk-op loads + a 31-step branchless compose chain: no 16KB staging, no
// votes, no load imbalance.

#define NN 256
#define MM 4096
#define LSTEPS 16              // time steps per k_main block == chunk size
#define NCHUNK (MM / LSTEPS)   // 256 chunks
#define NSUP   (NCHUNK / 16)   // 16 superchunks (256 steps each)
#define IDENT  0xFFFF          // identity op: MIN(0xFFFF)

// ws layout (bytes):
//   0      : int  codes[MM]                 16384 B
//   16384  : int  sup[NSUP*NN]              16384 B   superchunk ops, [s][row]
//   32768  : int4 cho[(NCHUNK/4)*NN]       262144 B   chunk ops, [chunkgroup][row], 4 chunks/int4
//   294912 : float pref[NN*(NN+3)/2]       132608 B

__device__ __forceinline__ int rowOff(int i) { return i * (i + 3) / 2; }

__device__ __forceinline__ int opcompose(int a, int b) {
    // apply a, then b
    int m = min(a & 0xFFFF, b & 0xFFFF);
    int r = (a & 0x10000) | m;
    return (b & 0x10000) ? b : r;
}

// K1 fused prep: blocks [0,NN) -> per-row softplus + exclusive prefix (wave-scan);
//                blocks [NN, NN+MM/256) -> step codes + per-row chunk/superchunk ops.
__global__ __launch_bounds__(NN) void k_prep(const float* __restrict__ raw,
                                             const float* __restrict__ h,
                                             const float* __restrict__ lin,
                                             float* __restrict__ pref,
                                             int* __restrict__ codes,
                                             int* __restrict__ sup,
                                             int4* __restrict__ cho) {
    int tid = threadIdx.x;
    if (blockIdx.x < NN) {
        int i = blockIdx.x;
        float sp = 0.f;
        if (tid <= i) {
            float x = raw[i * (i + 1) / 2 + tid];
            sp = (x > 20.f) ? x : log1pf(expf(x));
        }
        float v = sp;
        int lane = tid & 63, wid = tid >> 6;
        #pragma unroll
        for (int o = 1; o < 64; o <<= 1) {
            float n = __shfl_up(v, o);
            if (lane >= o) v += n;
        }
        __shared__ float wsum[4];
        if (lane == 63) wsum[wid] = v;
        __syncthreads();
        float off = 0.f;
        for (int w = 0; w < wid; ++w) off += wsum[w];
        v += off;
        int base = rowOff(i);
        if (tid == 0) pref[base] = 0.f;
        if (tid <= i) pref[base + tid + 1] = v;   // exclusive prefix; [base+i+1] = row total
    } else {
        __shared__ float slin[NN];
        __shared__ __align__(16) int scodes[NN];
        slin[tid] = lin[tid];
        __syncthreads();
        int e = blockIdx.x - NN;                  // event block: 256 steps = 16 chunks
        int k = e * NN + tid;
        float hc = h[k];
        float hp = (k == 0) ? 1.0f : h[k - 1];    // hs[0] = -H_MIN = 1.0
        // arithmetic index guess (lin ~ linspace(-1,1,256)), then exact fp32 verify
        double td = ((double)hc + 1.0) * 127.5;
        int code;
        if (hc > hp) {
            int g = (int)ceil(td);                // iup = #{lin < hc}
            while (g < NN && slin[g] < hc) ++g;   // executes 0..1 times
            while (g > 0 && slin[g - 1] >= hc) --g;
            code = (g << 16) | 0xFFFF;            // up: jdn = INF
        } else if (hc < hp) {
            int g = (int)floor(td) + 1;           // jdn = #{lin <= hc}
            while (g < NN && slin[g] <= hc) ++g;
            while (g > 0 && slin[g - 1] > hc) --g;
            code = g;                             // down: iup = 0
        } else {
            code = 0xFFFF;                        // no event: identity
        }
        codes[k] = code;
        scodes[tid] = code;
        __syncthreads();

        // Phase 2: thread = row i. Build 16 chunk ops + 1 superchunk op.
        const int i = tid;
        const int4* s4 = (const int4*)scodes;     // broadcast reads (uniform addr)
        int cop[16];
        #pragma unroll
        for (int u = 0; u < 16; ++u) {
            int4 q0 = s4[u * 4 + 0];
            int4 q1 = s4[u * 4 + 1];
            int4 q2 = s4[u * 4 + 2];
            int4 q3 = s4[u * 4 + 3];
            int cb[16] = { q0.x, q0.y, q0.z, q0.w, q1.x, q1.y, q1.z, q1.w,
                           q2.x, q2.y, q2.z, q2.w, q3.x, q3.y, q3.z, q3.w };
            int run = IDENT;
            #pragma unroll
            for (int s = 0; s < 16; ++s) {        // ascending time
                int code = cb[s];
                bool cov = i < (code >> 16);
                int mn = (run & 0x10000) | min(run & 0xFFFF, code & 0xFFFF);
                run = cov ? (0x10000 | (i + 1)) : mn;
            }
            cop[u] = run;
        }
        int sop = IDENT;
        #pragma unroll
        for (int u = 0; u < 16; ++u) sop = opcompose(sop, cop[u]);
        sup[e * NN + i] = sop;                    // coalesced across rows
        #pragma unroll
        for (int g = 0; g < 4; ++g)               // coalesced int4 across rows
            cho[(e * 4 + g) * NN + i] =
                make_int4(cop[4 * g + 0], cop[4 * g + 1], cop[4 * g + 2], cop[4 * g + 3]);
    }
}

// K2: block b owns steps [T, T+16). Incoming state = compose(superops[0..s-1],
// chunkops[s*16..b-1]) applied to init — deterministic, uniform cost, no LDS staging.
__global__ __launch_bounds__(NN) void k_main(const int* __restrict__ codes,
                                             const int* __restrict__ sup,
                                             const int4* __restrict__ cho,
                                             const float* __restrict__ pref,
                                             float* __restrict__ out) {
    __shared__ int sc16[LSTEPS];
    __shared__ float sPart[LSTEPS + 1][4];
    int tid = threadIdx.x;
    const int i = tid;                         // thread == row
    const int b = blockIdx.x;
    const int T = b * LSTEPS;
    const int s = b >> 4;                      // superchunk index

    if (tid < LSTEPS) sc16[tid] = codes[T + tid];

    int base = rowOff(i);
    float rowtot = pref[base + i + 1];

    // Prefix composition, ascending time: full superchunks, then chunks within ours.
    int run = IDENT;
    #pragma unroll
    for (int sp = 0; sp < NSUP - 1; ++sp) {    // <=15 coalesced b32 loads
        int v = sup[sp * NN + i];
        run = opcompose(run, (sp < s) ? v : IDENT);
    }
    #pragma unroll
    for (int g = 0; g < 4; ++g) {              // 4 coalesced int4 loads
        int4 q = cho[(s * 4 + g) * NN + i];
        int C = s * 16 + g * 4;
        run = opcompose(run, (C + 0 < b) ? q.x : IDENT);
        run = opcompose(run, (C + 1 < b) ? q.y : IDENT);
        run = opcompose(run, (C + 2 < b) ? q.z : IDENT);
        run = opcompose(run, (C + 3 < b) ? q.w : IDENT);
    }

    // Apply to initial state (rows 0..254: c=i+1; row 255: c=0).
    int c = (i == NN - 1) ? 0 : i + 1;
    { int m = run & 0xFFFF; c = (run & 0x10000) ? m : min(c, m); }

    __syncthreads();                           // sc16 ready

    // Forward: 16 states, 16 gathers, one fused reduction pass.
    float vals[LSTEPS];
    #pragma unroll
    for (int kk = 0; kk < LSTEPS; ++kk) {
        int code = sc16[kk];
        c = (i < (code >> 16)) ? (i + 1) : min(c, code & 0xFFFF);
        vals[kk] = pref[base + c];
    }
    #pragma unroll
    for (int kk = 0; kk <= LSTEPS; ++kk) {
        float v = (kk < LSTEPS) ? vals[kk] : rowtot;
        v += __shfl_xor(v, 1);  v += __shfl_xor(v, 2);  v += __shfl_xor(v, 4);
        v += __shfl_xor(v, 8);  v += __shfl_xor(v, 16); v += __shfl_xor(v, 32);
        if ((tid & 63) == 0) sPart[kk][tid >> 6] = v;
    }
    __syncthreads();
    if (tid < LSTEPS) {
        float sm = sPart[tid][0] + sPart[tid][1] + sPart[tid][2] + sPart[tid][3];
        float st = sPart[LSTEPS][0] + sPart[LSTEPS][1] + sPart[LSTEPS][2] + sPart[LSTEPS][3];
        out[T + tid] = (2.f * sm - st) / st;
    }
}

extern "C" void kernel_launch(void* const* d_in, const int* in_sizes, int n_in,
                              void* d_out, int out_size, void* d_ws, size_t ws_size,
                              hipStream_t stream) {
    const float* h   = (const float*)d_in[0];   // (M,)
    const float* raw = (const float*)d_in[1];   // (N*(N+1)/2,)
    const float* xx  = (const float*)d_in[2];   // (N,N): row 0 is lin[0..N)
    // d_in[3] = yy (lin along rows) — not needed.

    int*   codes = (int*)d_ws;
    int*   sup   = (int*)((char*)d_ws + 16384);
    int4*  cho   = (int4*)((char*)d_ws + 32768);
    float* pref  = (float*)((char*)d_ws + 294912);

    k_prep<<<NN + MM / NN, NN, 0, stream>>>(raw, h, xx, pref, codes, sup, cho);
    k_main<<<NCHUNK, NN, 0, stream>>>(codes, sup, cho, pref, (float*)d_out);
}